// Round 1
// baseline (379.693 us; speedup 1.0000x reference)
//
#include <hip/hip_runtime.h>
#include <stdint.h>

#define S_LEN 2048
#define NB    4
#define DMOD  1024
#define NH    16
#define HD    64

typedef float f32x4 __attribute__((ext_vector_type(4)));
typedef short bf16x8 __attribute__((ext_vector_type(8)));
typedef unsigned short u16;

__device__ __forceinline__ u16 f32_to_bf16(float f) {
  union { float f; unsigned int u; } v; v.f = f;
  unsigned int r = v.u + 0x7fffu + ((v.u >> 16) & 1u);  // RNE
  return (u16)(r >> 16);
}

typedef __attribute__((address_space(1))) const unsigned int gu32;
typedef __attribute__((address_space(3))) unsigned int lu32;
__device__ __forceinline__ void async_copy16(const void* g, void* l) {
  __builtin_amdgcn_global_load_lds((gu32*)g, (lu32*)l, 16, 0, 0);
}

// ---------------- fp32 -> bf16 weight conversion ----------------
__global__ __launch_bounds__(256) void convert_kernel(const float* __restrict__ in,
                                                      u16* __restrict__ out, int n) {
  int i = (blockIdx.x * 256 + threadIdx.x) * 4;
  if (i >= n) return;
  float4 v = *(const float4*)(in + i);
  ushort4 o;
  o.x = f32_to_bf16(v.x); o.y = f32_to_bf16(v.y);
  o.z = f32_to_bf16(v.z); o.w = f32_to_bf16(v.w);
  *(ushort4*)(out + i) = o;
}

// ---------------- GEMM: C = A @ W^T (+bias)*scale ----------------
// MODE 0: A = fp32 X [S][NB][D] (per-batch rows), out bf16 [bh][s][dk]
// MODE 1: same A, out bf16 TRANSPOSED [bh][dk][s]   (for V)
// MODE 2: A = bf16 [NB][S][D], out fp32 [s][b][d]   (final projection)
template <int MODE>
__global__ __launch_bounds__(256) void gemm_tpl(const void* __restrict__ Aany,
                                                const u16* __restrict__ Bw,
                                                const float* __restrict__ bias,
                                                void* __restrict__ outp,
                                                float scale) {
  __shared__ u16 a_lds[128 * 32];
  __shared__ u16 b_lds[128 * 32];
  const int tid  = threadIdx.x;
  const int wid  = tid >> 6;
  const int lane = tid & 63;
  const int wm = wid >> 1, wn = wid & 1;   // 2x2 waves, 64x64 each
  const int bz = blockIdx.z;
  const int m0 = blockIdx.x * 128;
  const int n0 = blockIdx.y * 128;

  f32x4 acc[4][4] = {};

  for (int kt = 0; kt < 32; ++kt) {
    const int k0 = kt * 32;
    __syncthreads();
    // stage B tile (weights, bf16) via global_load_lds, swizzled source
    #pragma unroll
    for (int i = 0; i < 2; ++i) {
      int row = wid * 32 + i * 16 + (lane >> 2);
      int sc  = (lane & 3) ^ ((row >> 1) & 3);
      const u16* src = Bw + (size_t)(n0 + row) * 1024 + k0 + sc * 8;
      async_copy16(src, b_lds + wid * 1024 + i * 512);
    }
    if constexpr (MODE != 2) {
      // A = fp32, reg-stage + convert, swizzled ds_write
      int row = tid >> 1, half = tid & 1;
      const float* src = (const float*)Aany + ((size_t)(m0 + row) * NB + bz) * 1024 + k0 + half * 16;
      u16 tmp[16];
      #pragma unroll
      for (int i = 0; i < 4; ++i) {
        float4 v = *(const float4*)(src + i * 4);
        tmp[i*4+0] = f32_to_bf16(v.x); tmp[i*4+1] = f32_to_bf16(v.y);
        tmp[i*4+2] = f32_to_bf16(v.z); tmp[i*4+3] = f32_to_bf16(v.w);
      }
      #pragma unroll
      for (int c = 0; c < 2; ++c) {
        int chunk = half * 2 + c;
        int slot  = chunk ^ ((row >> 1) & 3);
        *(int4*)(a_lds + row * 32 + slot * 8) = *(const int4*)(tmp + c * 8);
      }
    } else {
      // A = bf16 rows, same async path as B
      #pragma unroll
      for (int i = 0; i < 2; ++i) {
        int row = wid * 32 + i * 16 + (lane >> 2);
        int sc  = (lane & 3) ^ ((row >> 1) & 3);
        const u16* src = (const u16*)Aany + ((size_t)bz * S_LEN + m0 + row) * 1024 + k0 + sc * 8;
        async_copy16(src, a_lds + wid * 1024 + i * 512);
      }
    }
    asm volatile("s_waitcnt vmcnt(0)" ::: "memory");
    __syncthreads();

    bf16x8 af[4], bfr[4];
    #pragma unroll
    for (int mi = 0; mi < 4; ++mi) {
      int row = wm * 64 + mi * 16 + (lane & 15);
      int ch  = (lane >> 4) ^ ((row >> 1) & 3);
      af[mi] = *(const bf16x8*)(a_lds + row * 32 + ch * 8);
    }
    #pragma unroll
    for (int ni = 0; ni < 4; ++ni) {
      int row = wn * 64 + ni * 16 + (lane & 15);
      int ch  = (lane >> 4) ^ ((row >> 1) & 3);
      bfr[ni] = *(const bf16x8*)(b_lds + row * 32 + ch * 8);
    }
    #pragma unroll
    for (int mi = 0; mi < 4; ++mi)
      #pragma unroll
      for (int ni = 0; ni < 4; ++ni)
        acc[mi][ni] = __builtin_amdgcn_mfma_f32_16x16x32_bf16(af[mi], bfr[ni], acc[mi][ni], 0, 0, 0);
  }

  // epilogue: C row = (lane>>4)*4 + r, col = lane&15 (m89-verified layout)
  #pragma unroll
  for (int ni = 0; ni < 4; ++ni) {
    int n = n0 + wn * 64 + ni * 16 + (lane & 15);
    float bv = bias[n];
    #pragma unroll
    for (int mi = 0; mi < 4; ++mi) {
      int sbase = m0 + wm * 64 + mi * 16 + ((lane >> 4) << 2);
      if constexpr (MODE == 0) {
        u16* o = (u16*)outp;
        int h = n >> 6, dk = n & 63;
        size_t base = (size_t)(bz * NH + h) * S_LEN;
        #pragma unroll
        for (int r = 0; r < 4; ++r)
          o[(base + sbase + r) * HD + dk] = f32_to_bf16((acc[mi][ni][r] + bv) * scale);
      } else if constexpr (MODE == 1) {
        int h = n >> 6, dk = n & 63;
        size_t idx = ((size_t)(bz * NH + h) * HD + dk) * S_LEN + sbase;
        ushort4 o4;
        o4.x = f32_to_bf16((acc[mi][ni][0] + bv) * scale);
        o4.y = f32_to_bf16((acc[mi][ni][1] + bv) * scale);
        o4.z = f32_to_bf16((acc[mi][ni][2] + bv) * scale);
        o4.w = f32_to_bf16((acc[mi][ni][3] + bv) * scale);
        *(ushort4*)((u16*)outp + idx) = o4;
      } else {
        float* o = (float*)outp;
        #pragma unroll
        for (int r = 0; r < 4; ++r)
          o[((size_t)(sbase + r) * NB + bz) * 1024 + n] = acc[mi][ni][r] + bv;
      }
    }
  }
}

// ---------------- flash attention ----------------
// Q pre-scaled by 0.125*log2(e); softmax in exp2 domain.
// Qb,Kb: [bh][s][dk] bf16 ; Vt: [bh][dk][s] bf16 ; Oatt: [b][s][h][dk] bf16
__global__ __launch_bounds__(512) void attn_kernel(const u16* __restrict__ Qb,
                                                   const u16* __restrict__ Kb,
                                                   const u16* __restrict__ Vt,
                                                   u16* __restrict__ Oatt) {
  __shared__ u16 k_lds[64 * 64];
  __shared__ u16 v_lds[64 * 64];
  __shared__ u16 p_lds[8][16 * 88];   // stride 88 elems: 16B-aligned rows, conflict-free
  const int tid = threadIdx.x;
  const int w = tid >> 6, lane = tid & 63;
  const int qt = blockIdx.x, h = blockIdx.y, b = blockIdx.z;
  const int bh = b * NH + h;
  const int q0 = qt * 128 + w * 16;

  bf16x8 qf[2];
  {
    const u16* qp = Qb + ((size_t)bh * S_LEN + q0 + (lane & 15)) * HD + ((lane >> 4) * 8);
    qf[0] = *(const bf16x8*)(qp);
    qf[1] = *(const bf16x8*)(qp + 32);
  }
  f32x4 acc[4] = {};
  float mrow[4] = {-1e30f, -1e30f, -1e30f, -1e30f};
  float lrow[4] = {0.f, 0.f, 0.f, 0.f};

  for (int kb = 0; kb < 32; ++kb) {
    const int kbase = kb * 64;
    __syncthreads();
    {
      int j  = w * 8 + (lane >> 3);
      int sc = (lane & 7) ^ (j & 7);
      async_copy16(Kb + ((size_t)bh * S_LEN + kbase + j) * HD + sc * 8, k_lds + w * 512);
      async_copy16(Vt + ((size_t)bh * HD + j) * S_LEN + kbase + sc * 8, v_lds + w * 512);
    }
    asm volatile("s_waitcnt vmcnt(0)" ::: "memory");
    __syncthreads();

    // S-tile [16 q x 64 k]
    f32x4 sfr[4];
    #pragma unroll
    for (int nt = 0; nt < 4; ++nt) {
      f32x4 sa = {0.f, 0.f, 0.f, 0.f};
      #pragma unroll
      for (int ks = 0; ks < 2; ++ks) {
        int j  = nt * 16 + (lane & 15);
        int ch = (ks * 4 + (lane >> 4)) ^ (j & 7);
        bf16x8 kf = *(const bf16x8*)(k_lds + j * 64 + ch * 8);
        sa = __builtin_amdgcn_mfma_f32_16x16x32_bf16(qf[ks], kf, sa, 0, 0, 0);
      }
      sfr[nt] = sa;
    }
    // online softmax (base-2), wave-parallel row reduce across 16-lane groups
    float pm[4], rs[4] = {0.f, 0.f, 0.f, 0.f};
    #pragma unroll
    for (int r = 0; r < 4; ++r)
      pm[r] = fmaxf(fmaxf(sfr[0][r], sfr[1][r]), fmaxf(sfr[2][r], sfr[3][r]));
    #pragma unroll
    for (int off = 1; off <= 8; off <<= 1)
      #pragma unroll
      for (int r = 0; r < 4; ++r) pm[r] = fmaxf(pm[r], __shfl_xor(pm[r], off));
    float alpha[4];
    #pragma unroll
    for (int r = 0; r < 4; ++r) {
      float mn = fmaxf(mrow[r], pm[r]);
      alpha[r] = exp2f(mrow[r] - mn);
      mrow[r] = mn;
    }
    u16 pb[4][4];
    #pragma unroll
    for (int nt = 0; nt < 4; ++nt)
      #pragma unroll
      for (int r = 0; r < 4; ++r) {
        float p = exp2f(sfr[nt][r] - mrow[r]);
        rs[r] += p;
        pb[nt][r] = f32_to_bf16(p);
      }
    #pragma unroll
    for (int off = 1; off <= 8; off <<= 1)
      #pragma unroll
      for (int r = 0; r < 4; ++r) rs[r] += __shfl_xor(rs[r], off);
    #pragma unroll
    for (int r = 0; r < 4; ++r) lrow[r] = lrow[r] * alpha[r] + rs[r];
    #pragma unroll
    for (int dt = 0; dt < 4; ++dt)
      #pragma unroll
      for (int r = 0; r < 4; ++r) acc[dt][r] *= alpha[r];

    // P: C-layout -> LDS -> A-fragment layout (per-wave buffer, no barrier)
    u16* pw = &p_lds[w][0];
    #pragma unroll
    for (int nt = 0; nt < 4; ++nt)
      #pragma unroll
      for (int r = 0; r < 4; ++r)
        pw[((lane >> 4) * 4 + r) * 88 + nt * 16 + (lane & 15)] = pb[nt][r];

    #pragma unroll
    for (int dt = 0; dt < 4; ++dt) {
      #pragma unroll
      for (int ks = 0; ks < 2; ++ks) {
        bf16x8 pa = *(const bf16x8*)(pw + (lane & 15) * 88 + ks * 32 + (lane >> 4) * 8);
        int vr = dt * 16 + (lane & 15);
        int ch = (ks * 4 + (lane >> 4)) ^ (vr & 7);
        bf16x8 vf = *(const bf16x8*)(v_lds + vr * 64 + ch * 8);
        acc[dt] = __builtin_amdgcn_mfma_f32_16x16x32_bf16(pa, vf, acc[dt], 0, 0, 0);
      }
    }
  }
  // epilogue: O = acc / l  -> Oatt [b][s][h][dk]
  #pragma unroll
  for (int dt = 0; dt < 4; ++dt) {
    #pragma unroll
    for (int r = 0; r < 4; ++r) {
      int srow = q0 + ((lane >> 4) << 2) + r;
      float o = acc[dt][r] / lrow[r];
      Oatt[(((size_t)b * S_LEN + srow) * NH + h) * HD + dt * 16 + (lane & 15)] = f32_to_bf16(o);
    }
  }
}

// ---------------- launch ----------------
extern "C" void kernel_launch(void* const* d_in, const int* in_sizes, int n_in,
                              void* d_out, int out_size, void* d_ws, size_t ws_size,
                              hipStream_t stream) {
  const float* Xq = (const float*)d_in[0];
  const float* Xk = (const float*)d_in[1];
  const float* Xv = (const float*)d_in[2];
  const float* Wq = (const float*)d_in[3];
  const float* bq = (const float*)d_in[4];
  const float* Wk = (const float*)d_in[5];
  const float* bk = (const float*)d_in[6];
  const float* Wv = (const float*)d_in[7];
  const float* bv = (const float*)d_in[8];
  const float* Wo = (const float*)d_in[9];
  const float* bo = (const float*)d_in[10];

  // workspace layout (bf16), total ~75.5 MB
  u16* Wqb = (u16*)d_ws;
  u16* Wkb = Wqb + (1 << 20);
  u16* Wvb = Wkb + (1 << 20);
  u16* Wob = Wvb + (1 << 20);
  u16* Qb  = Wob + (1 << 20);
  const size_t QKV = (size_t)64 * S_LEN * HD;  // 8388608
  u16* Kb  = Qb + QKV;
  u16* Vt  = Kb + QKV;
  u16* Oat = Vt + QKV;

  convert_kernel<<<1024, 256, 0, stream>>>(Wq, Wqb, 1 << 20);
  convert_kernel<<<1024, 256, 0, stream>>>(Wk, Wkb, 1 << 20);
  convert_kernel<<<1024, 256, 0, stream>>>(Wv, Wvb, 1 << 20);
  convert_kernel<<<1024, 256, 0, stream>>>(Wo, Wob, 1 << 20);

  dim3 gg(16, 8, 4);
  // Q pre-scaled by (1/sqrt(64)) * log2(e) so softmax runs in exp2 domain
  gemm_tpl<0><<<gg, 256, 0, stream>>>(Xq, Wqb, bq, Qb, 0.125f * 1.4426950408889634f);
  gemm_tpl<0><<<gg, 256, 0, stream>>>(Xk, Wkb, bk, Kb, 1.0f);
  gemm_tpl<1><<<gg, 256, 0, stream>>>(Xv, Wvb, bv, Vt, 1.0f);

  attn_kernel<<<dim3(16, 16, 4), 512, 0, stream>>>(Qb, Kb, Vt, Oat);

  gemm_tpl<2><<<gg, 256, 0, stream>>>(Oat, Wob, bo, d_out, 1.0f);
}

// Round 2
// 298.588 us; speedup vs baseline: 1.2716x; 1.2716x over previous
//
#include <hip/hip_runtime.h>
#include <stdint.h>

#define S_LEN 2048
#define NB    4
#define DMOD  1024
#define NH    16
#define HD    64

typedef float f32x4 __attribute__((ext_vector_type(4)));
typedef float f32x16 __attribute__((ext_vector_type(16)));
typedef short bf16x8 __attribute__((ext_vector_type(8)));
typedef unsigned int u32x4 __attribute__((ext_vector_type(4)));
typedef unsigned short u16;
typedef unsigned int u32;

__device__ __forceinline__ u16 f32_to_bf16(float f) {
  union { float f; unsigned int u; } v; v.f = f;
  unsigned int r = v.u + 0x7fffu + ((v.u >> 16) & 1u);  // RNE
  return (u16)(r >> 16);
}

typedef __attribute__((address_space(1))) const unsigned int gu32;
typedef __attribute__((address_space(3))) unsigned int lu32;
__device__ __forceinline__ void async_copy16(const void* g, void* l) {
  __builtin_amdgcn_global_load_lds((gu32*)g, (lu32*)l, 16, 0, 0);
}

// ---------------- fp32 -> bf16 weight conversion ----------------
__global__ __launch_bounds__(256) void convert_kernel(const float* __restrict__ in,
                                                      u16* __restrict__ out, int n) {
  int i = (blockIdx.x * 256 + threadIdx.x) * 4;
  if (i >= n) return;
  float4 v = *(const float4*)(in + i);
  ushort4 o;
  o.x = f32_to_bf16(v.x); o.y = f32_to_bf16(v.y);
  o.z = f32_to_bf16(v.z); o.w = f32_to_bf16(v.w);
  *(ushort4*)(out + i) = o;
}

// ---------------- GEMM: C = A @ W^T (+bias)*scale ----------------
// MODE 0: A = fp32 X [S][NB][D] (per-batch rows), out bf16 [bh][s][dk]
// MODE 1: same A, out bf16 TRANSPOSED [bh][dk][s]   (for V)
// MODE 2: A = bf16 [NB][S][D], out fp32 [s][b][d]   (final projection)
template <int MODE>
__global__ __launch_bounds__(256) void gemm_tpl(const void* __restrict__ Aany,
                                                const u16* __restrict__ Bw,
                                                const float* __restrict__ bias,
                                                void* __restrict__ outp,
                                                float scale) {
  __shared__ u16 a_lds[128 * 32];
  __shared__ u16 b_lds[128 * 32];
  const int tid  = threadIdx.x;
  const int wid  = tid >> 6;
  const int lane = tid & 63;
  const int wm = wid >> 1, wn = wid & 1;   // 2x2 waves, 64x64 each
  const int bz = blockIdx.z;
  const int m0 = blockIdx.x * 128;
  const int n0 = blockIdx.y * 128;

  f32x4 acc[4][4] = {};

  for (int kt = 0; kt < 32; ++kt) {
    const int k0 = kt * 32;
    __syncthreads();
    // stage B tile (weights, bf16) via global_load_lds, swizzled source
    #pragma unroll
    for (int i = 0; i < 2; ++i) {
      int row = wid * 32 + i * 16 + (lane >> 2);
      int sc  = (lane & 3) ^ ((row >> 1) & 3);
      const u16* src = Bw + (size_t)(n0 + row) * 1024 + k0 + sc * 8;
      async_copy16(src, b_lds + wid * 1024 + i * 512);
    }
    if constexpr (MODE != 2) {
      // A = fp32, reg-stage + convert, swizzled ds_write
      int row = tid >> 1, half = tid & 1;
      const float* src = (const float*)Aany + ((size_t)(m0 + row) * NB + bz) * 1024 + k0 + half * 16;
      u16 tmp[16];
      #pragma unroll
      for (int i = 0; i < 4; ++i) {
        float4 v = *(const float4*)(src + i * 4);
        tmp[i*4+0] = f32_to_bf16(v.x); tmp[i*4+1] = f32_to_bf16(v.y);
        tmp[i*4+2] = f32_to_bf16(v.z); tmp[i*4+3] = f32_to_bf16(v.w);
      }
      #pragma unroll
      for (int c = 0; c < 2; ++c) {
        int chunk = half * 2 + c;
        int slot  = chunk ^ ((row >> 1) & 3);
        *(int4*)(a_lds + row * 32 + slot * 8) = *(const int4*)(tmp + c * 8);
      }
    } else {
      // A = bf16 rows, same async path as B
      #pragma unroll
      for (int i = 0; i < 2; ++i) {
        int row = wid * 32 + i * 16 + (lane >> 2);
        int sc  = (lane & 3) ^ ((row >> 1) & 3);
        const u16* src = (const u16*)Aany + ((size_t)bz * S_LEN + m0 + row) * 1024 + k0 + sc * 8;
        async_copy16(src, a_lds + wid * 1024 + i * 512);
      }
    }
    asm volatile("s_waitcnt vmcnt(0)" ::: "memory");
    __syncthreads();

    bf16x8 af[4], bfr[4];
    #pragma unroll
    for (int mi = 0; mi < 4; ++mi) {
      int row = wm * 64 + mi * 16 + (lane & 15);
      int ch  = (lane >> 4) ^ ((row >> 1) & 3);
      af[mi] = *(const bf16x8*)(a_lds + row * 32 + ch * 8);
    }
    #pragma unroll
    for (int ni = 0; ni < 4; ++ni) {
      int row = wn * 64 + ni * 16 + (lane & 15);
      int ch  = (lane >> 4) ^ ((row >> 1) & 3);
      bfr[ni] = *(const bf16x8*)(b_lds + row * 32 + ch * 8);
    }
    #pragma unroll
    for (int mi = 0; mi < 4; ++mi)
      #pragma unroll
      for (int ni = 0; ni < 4; ++ni)
        acc[mi][ni] = __builtin_amdgcn_mfma_f32_16x16x32_bf16(af[mi], bfr[ni], acc[mi][ni], 0, 0, 0);
  }

  // epilogue: C row = (lane>>4)*4 + r, col = lane&15 (m89-verified layout)
  #pragma unroll
  for (int ni = 0; ni < 4; ++ni) {
    int n = n0 + wn * 64 + ni * 16 + (lane & 15);
    float bv = bias[n];
    #pragma unroll
    for (int mi = 0; mi < 4; ++mi) {
      int sbase = m0 + wm * 64 + mi * 16 + ((lane >> 4) << 2);
      if constexpr (MODE == 0) {
        u16* o = (u16*)outp;
        int h = n >> 6, dk = n & 63;
        size_t base = (size_t)(bz * NH + h) * S_LEN;
        #pragma unroll
        for (int r = 0; r < 4; ++r)
          o[(base + sbase + r) * HD + dk] = f32_to_bf16((acc[mi][ni][r] + bv) * scale);
      } else if constexpr (MODE == 1) {
        int h = n >> 6, dk = n & 63;
        size_t idx = ((size_t)(bz * NH + h) * HD + dk) * S_LEN + sbase;
        ushort4 o4;
        o4.x = f32_to_bf16((acc[mi][ni][0] + bv) * scale);
        o4.y = f32_to_bf16((acc[mi][ni][1] + bv) * scale);
        o4.z = f32_to_bf16((acc[mi][ni][2] + bv) * scale);
        o4.w = f32_to_bf16((acc[mi][ni][3] + bv) * scale);
        *(ushort4*)((u16*)outp + idx) = o4;
      } else {
        float* o = (float*)outp;
        #pragma unroll
        for (int r = 0; r < 4; ++r)
          o[((size_t)(sbase + r) * NB + bz) * 1024 + n] = acc[mi][ni][r] + bv;
      }
    }
  }
}

// ---------------- flash attention, 8-wave 32x32 swapped-QK ----------------
// Q pre-scaled by 0.125*log2(e); softmax in exp2 domain.
// Qb,Kb: [bh][s][dk] bf16 ; Vt: [bh][dk][s] bf16 ; Oatt: [b][s][h][dk] bf16
// Per wave: 32 Q rows. Per KV64 tile: pk = mfma(Kfrag, Qfrag) -> P[k][q],
// lane holds 32 P values of q=lane&31 (full tile row across lane pair).
// In-register softmax; PV A-frags built via cvt_pk + shfl_xor(32).
__global__ __launch_bounds__(512) void attn_kernel(const u16* __restrict__ Qb,
                                                   const u16* __restrict__ Kb,
                                                   const u16* __restrict__ Vt,
                                                   u16* __restrict__ Oatt) {
  __shared__ u16 kbuf[2][64 * 64];
  __shared__ u16 vbuf[2][64 * 64];   // V^T tile: [d=64][k=64]
  __shared__ float alds[8][32];
  const int tid = threadIdx.x;
  const int w = tid >> 6, lane = tid & 63;
  const int hi = lane >> 5, l31 = lane & 31;
  const int h = blockIdx.y, b = blockIdx.z;
  const int bh = b * NH + h;
  const int q0 = blockIdx.x * 256 + w * 32;

  // Q fragments (B-operand: col=lane&31 = q row, k = hi*8 + j, 4 dk-steps)
  bf16x8 qf[4];
  {
    const u16* qp = Qb + ((size_t)bh * S_LEN + q0 + l31) * HD + hi * 8;
    #pragma unroll
    for (int s = 0; s < 4; ++s) qf[s] = *(const bf16x8*)(qp + s * 16);
  }

  f32x16 acc0 = {}, acc1 = {}, accl = {};
  float m_run = -1e30f;
  const bf16x8 ones = {(short)0x3F80, (short)0x3F80, (short)0x3F80, (short)0x3F80,
                       (short)0x3F80, (short)0x3F80, (short)0x3F80, (short)0x3F80};

  // staging addresses: wave w covers rows 8w..8w+7 of the 64-row tile,
  // linear LDS dest (base + lane*16), XOR-pre-swizzled global source chunk.
  const int rl = w * 8 + (lane >> 3);
  const int cg = (lane & 7) ^ (rl & 7);
  const u16* ksrc = Kb + ((size_t)bh * S_LEN + rl) * HD + cg * 8;
  const u16* vsrc = Vt + ((size_t)bh * HD + rl) * S_LEN + cg * 8;

  async_copy16(ksrc, &kbuf[0][w * 512]);
  async_copy16(vsrc, &vbuf[0][w * 512]);
  asm volatile("s_waitcnt vmcnt(0)" ::: "memory");
  __syncthreads();

  for (int kb = 0; kb < 32; ++kb) {
    const int cur = kb & 1;
    if (kb + 1 < 32) {  // stage next tile early (2-phase)
      async_copy16(ksrc + (size_t)(kb + 1) * 64 * HD, &kbuf[cur ^ 1][w * 512]);
      async_copy16(vsrc + (kb + 1) * 64, &vbuf[cur ^ 1][w * 512]);
    }
    const u16* KL = kbuf[cur];
    const u16* VL = vbuf[cur];

    // ---- QK^T (swapped): pk[kt] = K[kt] x Q, D[k][q], col q = lane&31
    f32x16 pk0 = {}, pk1 = {};
    {
      const int rb = l31 * 64;
      const int r7 = l31 & 7;
      #pragma unroll
      for (int s = 0; s < 4; ++s) {
        const int ch = ((2 * s + hi) ^ r7) * 8;
        bf16x8 kf0 = *(const bf16x8*)(KL + rb + ch);
        bf16x8 kf1 = *(const bf16x8*)(KL + rb + 2048 + ch);
        pk0 = __builtin_amdgcn_mfma_f32_32x32x16_bf16(kf0, qf[s], pk0, 0, 0, 0);
        pk1 = __builtin_amdgcn_mfma_f32_32x32x16_bf16(kf1, qf[s], pk1, 0, 0, 0);
      }
    }

    // ---- online softmax, in-register (q = lane&31 domain)
    float t8[8];
    #pragma unroll
    for (int r = 0; r < 8; ++r)
      t8[r] = fmaxf(fmaxf(pk0[r], pk0[r + 8]), fmaxf(pk1[r], pk1[r + 8]));
    float pm = fmaxf(fmaxf(fmaxf(t8[0], t8[1]), fmaxf(t8[2], t8[3])),
                     fmaxf(fmaxf(t8[4], t8[5]), fmaxf(t8[6], t8[7])));
    pm = fmaxf(pm, __shfl_xor(pm, 32));

    if (!__all(pm <= m_run + 8.0f)) {   // defer-max: rescale is rare
      float mn = fmaxf(m_run, pm);
      float al = exp2f(m_run - mn);
      m_run = mn;
      if (lane < 32) alds[w][l31] = al;   // broadcast to C-row domain
      #pragma unroll
      for (int r = 0; r < 16; ++r) {
        float av = alds[w][(r & 3) + 8 * (r >> 2) + 4 * hi];
        acc0[r] *= av; acc1[r] *= av; accl[r] *= av;
      }
    }
    #pragma unroll
    for (int r = 0; r < 16; ++r) {
      pk0[r] = exp2f(pk0[r] - m_run);
      pk1[r] = exp2f(pk1[r] - m_run);
    }

    // ---- P -> bf16 A-fragments in-register (cvt_pk + cross-half shfl)
    u32 c0[8], c1[8];
    #pragma unroll
    for (int i = 0; i < 8; ++i) {
      float a0 = pk0[2 * i], b0 = pk0[2 * i + 1];
      float a1 = pk1[2 * i], b1 = pk1[2 * i + 1];
      asm("v_cvt_pk_bf16_f32 %0, %1, %2" : "=v"(c0[i]) : "v"(a0), "v"(b0));
      asm("v_cvt_pk_bf16_f32 %0, %1, %2" : "=v"(c1[i]) : "v"(a1), "v"(b1));
    }
    u32 pa[4][4];
    #pragma unroll
    for (int half = 0; half < 2; ++half) {
      {
        u32 x0 = c0[half*4+0], x1 = c0[half*4+1], y0 = c0[half*4+2], y1 = c0[half*4+3];
        u32 X0 = __shfl_xor((int)x0, 32), X1 = __shfl_xor((int)x1, 32);
        u32 Y0 = __shfl_xor((int)y0, 32), Y1 = __shfl_xor((int)y1, 32);
        pa[half][0] = hi ? Y0 : x0;
        pa[half][1] = hi ? Y1 : x1;
        pa[half][2] = hi ? y0 : X0;
        pa[half][3] = hi ? y1 : X1;
      }
      {
        u32 x0 = c1[half*4+0], x1 = c1[half*4+1], y0 = c1[half*4+2], y1 = c1[half*4+3];
        u32 X0 = __shfl_xor((int)x0, 32), X1 = __shfl_xor((int)x1, 32);
        u32 Y0 = __shfl_xor((int)y0, 32), Y1 = __shfl_xor((int)y1, 32);
        pa[2 + half][0] = hi ? Y0 : x0;
        pa[2 + half][1] = hi ? Y1 : x1;
        pa[2 + half][2] = hi ? y0 : X0;
        pa[2 + half][3] = hi ? y1 : X1;
      }
    }

    // ---- PV (+ row-sum via ones-B): acc rows = q (C layout), cols = d
    {
      const int rb0 = l31 * 64, rb1 = (32 + l31) * 64;
      const int r7 = l31 & 7;
      #pragma unroll
      for (int ks = 0; ks < 4; ++ks) {
        u32x4 pw = {pa[ks][0], pa[ks][1], pa[ks][2], pa[ks][3]};
        bf16x8 paf = __builtin_bit_cast(bf16x8, pw);
        const int chv = ((2 * ks + hi) ^ r7) * 8;
        bf16x8 vf0 = *(const bf16x8*)(VL + rb0 + chv);
        bf16x8 vf1 = *(const bf16x8*)(VL + rb1 + chv);
        acc0 = __builtin_amdgcn_mfma_f32_32x32x16_bf16(paf, vf0, acc0, 0, 0, 0);
        acc1 = __builtin_amdgcn_mfma_f32_32x32x16_bf16(paf, vf1, acc1, 0, 0, 0);
        accl = __builtin_amdgcn_mfma_f32_32x32x16_bf16(paf, ones, accl, 0, 0, 0);
      }
    }

    asm volatile("s_waitcnt vmcnt(0)" ::: "memory");
    __syncthreads();
  }

  // ---- epilogue: O = acc / l ; rows q = crow(r,hi), cols d = dt*32 + l31
  #pragma unroll
  for (int r = 0; r < 16; ++r) {
    const int q = q0 + (r & 3) + 8 * (r >> 2) + 4 * hi;
    u16* op = Oatt + ((size_t)b * S_LEN + q) * DMOD + h * HD;
    const float inv = 1.0f / accl[r];
    op[l31]      = f32_to_bf16(acc0[r] * inv);
    op[32 + l31] = f32_to_bf16(acc1[r] * inv);
  }
}

// ---------------- launch ----------------
extern "C" void kernel_launch(void* const* d_in, const int* in_sizes, int n_in,
                              void* d_out, int out_size, void* d_ws, size_t ws_size,
                              hipStream_t stream) {
  const float* Xq = (const float*)d_in[0];
  const float* Xk = (const float*)d_in[1];
  const float* Xv = (const float*)d_in[2];
  const float* Wq = (const float*)d_in[3];
  const float* bq = (const float*)d_in[4];
  const float* Wk = (const float*)d_in[5];
  const float* bk = (const float*)d_in[6];
  const float* Wv = (const float*)d_in[7];
  const float* bv = (const float*)d_in[8];
  const float* Wo = (const float*)d_in[9];
  const float* bo = (const float*)d_in[10];

  // workspace layout (bf16), total ~75.5 MB
  u16* Wqb = (u16*)d_ws;
  u16* Wkb = Wqb + (1 << 20);
  u16* Wvb = Wkb + (1 << 20);
  u16* Wob = Wvb + (1 << 20);
  u16* Qb  = Wob + (1 << 20);
  const size_t QKV = (size_t)64 * S_LEN * HD;  // 8388608
  u16* Kb  = Qb + QKV;
  u16* Vt  = Kb + QKV;
  u16* Oat = Vt + QKV;

  convert_kernel<<<1024, 256, 0, stream>>>(Wq, Wqb, 1 << 20);
  convert_kernel<<<1024, 256, 0, stream>>>(Wk, Wkb, 1 << 20);
  convert_kernel<<<1024, 256, 0, stream>>>(Wv, Wvb, 1 << 20);
  convert_kernel<<<1024, 256, 0, stream>>>(Wo, Wob, 1 << 20);

  dim3 gg(16, 8, 4);
  // Q pre-scaled by (1/sqrt(64)) * log2(e) so softmax runs in exp2 domain
  gemm_tpl<0><<<gg, 256, 0, stream>>>(Xq, Wqb, bq, Qb, 0.125f * 1.4426950408889634f);
  gemm_tpl<0><<<gg, 256, 0, stream>>>(Xk, Wkb, bk, Kb, 1.0f);
  gemm_tpl<1><<<gg, 256, 0, stream>>>(Xv, Wvb, bv, Vt, 1.0f);

  attn_kernel<<<dim3(8, 16, 4), 512, 0, stream>>>(Qb, Kb, Vt, Oat);

  gemm_tpl<2><<<gg, 256, 0, stream>>>(Oat, Wob, bo, d_out, 1.0f);
}